// Round 9
// baseline (712.017 us; speedup 1.0000x reference)
//
#include <hip/hip_runtime.h>
#include <hip/hip_bf16.h>

// Problem constants
#define NB 32
#define NC 256
#define NHW 3136                 // 56*56
#define NA 25690112ull           // NB*NC*NHW elements (one NCHW tensor)
#define NPW 3328                 // padded windowed plane: 64 windows * 52
#define LTS 396                  // xnt_make2 LDS row stride (ushorts, mult of 4)

typedef __attribute__((ext_vector_type(8))) short bf16x8;
typedef __attribute__((ext_vector_type(4))) float f32x4;

// Window mapping: h=h1*8+j1, w=w1*8+j2; j=j1*8+j2 (0..63), p=h1*7+w1 (0..48).
// PADDED windowed linear index n' = j*52 + p (p in [0,52), p>=49 = pad).

static __device__ __forceinline__ unsigned short f2bu(float f) {
    union { __hip_bfloat16 h; unsigned short u; } c;
    c.h = __float2bfloat16(f);
    return c.u;
}
static __device__ __forceinline__ float bu2f(unsigned short us) {
    union { unsigned short u; __hip_bfloat16 h; } c;
    c.u = us;
    return __bfloat162float(c.h);
}

// ---------------------------------------------------------------------------
// K1a: BatchNorm partial sums. Grid (256 c, 8 bq).
// ---------------------------------------------------------------------------
__launch_bounds__(256)
__global__ void bn_part(const float* __restrict__ x, float* __restrict__ part)
{
    const int c = blockIdx.x, bq = blockIdx.y;
    const int tid = threadIdx.x;
    float s = 0.f, s2 = 0.f;
    for (int b = bq * 4; b < bq * 4 + 4; ++b) {
        const float4* p = reinterpret_cast<const float4*>(x + ((size_t)b * NC + c) * NHW);
        for (int i = tid; i < 784; i += 256) {
            const float4 v = p[i];
            s += v.x + v.y + v.z + v.w;
            s2 = fmaf(v.x, v.x, s2); s2 = fmaf(v.y, v.y, s2);
            s2 = fmaf(v.z, v.z, s2); s2 = fmaf(v.w, v.w, s2);
        }
    }
    __shared__ float r1[256], r2[256];
    r1[tid] = s; r2[tid] = s2;
    __syncthreads();
    for (int off = 128; off > 0; off >>= 1) {
        if (tid < off) { r1[tid] += r1[tid + off]; r2[tid] += r2[tid + off]; }
        __syncthreads();
    }
    if (tid == 0) {
        part[(c * 8 + bq) * 2] = r1[0];
        part[(c * 8 + bq) * 2 + 1] = r2[0];
    }
}

// ---------------------------------------------------------------------------
// K1b: finalize BN affine (a,b), combined dw weights, bias sum, bf16 weights.
// ---------------------------------------------------------------------------
__launch_bounds__(256)
__global__ void bn_fin(const float* __restrict__ part,
                       const float* __restrict__ gamma, const float* __restrict__ beta,
                       const float* __restrict__ w3, const float* __restrict__ b3,
                       const float* __restrict__ w5, const float* __restrict__ b5,
                       const float* __restrict__ w7, const float* __restrict__ b7,
                       const float* __restrict__ qkvw,
                       const float* __restrict__ fiw, const float* __restrict__ fow,
                       float* __restrict__ ab, float* __restrict__ wcomb,
                       float* __restrict__ bsum, __hip_bfloat16* __restrict__ Wb,
                       __hip_bfloat16* __restrict__ Wfb, __hip_bfloat16* __restrict__ Wob)
{
    const int c = blockIdx.x;
    const int tid = threadIdx.x;

    if (tid < 49) {
        const int ty = tid / 7, tx = tid % 7;
        float wv = w7[c * 49 + tid];
        if (ty >= 1 && ty <= 5 && tx >= 1 && tx <= 5) wv += w5[c * 25 + (ty - 1) * 5 + (tx - 1)];
        if (ty >= 2 && ty <= 4 && tx >= 2 && tx <= 4) wv += w3[c * 9 + (ty - 2) * 3 + (tx - 2)];
        wcomb[c * 49 + tid] = 0.25f * wv;
    }
    if (tid == 63) bsum[c] = 0.25f * (b3[c] + b5[c] + b7[c]);

#pragma unroll
    for (int r = 0; r < 3; ++r) {
        const int o = 3 * c + r;
        Wb[o * 256 + tid] = __float2bfloat16(qkvw[o * 256 + tid]);
    }
    Wfb[c * 256 + tid] = __float2bfloat16(fiw[c * 256 + tid]);
    Wob[c * 256 + tid] = __float2bfloat16(fow[c * 256 + tid]);

    if (tid == 0) {
        float s = 0.f, s2 = 0.f;
#pragma unroll
        for (int q = 0; q < 8; ++q) {
            s += part[(c * 8 + q) * 2];
            s2 += part[(c * 8 + q) * 2 + 1];
        }
        const float inv_n = 1.f / (float)((size_t)NB * NHW);
        const float mean = s * inv_n;
        const float var = s2 * inv_n - mean * mean;
        const float a = gamma[c] / sqrtf(var + 1e-5f);
        ab[c] = a;
        ab[NC + c] = beta[c] - mean * a;
    }
}

// ---------------------------------------------------------------------------
// K1.5: xn = a*x+b applied once; emits PADDED-WINDOWED outputs:
//   XNt bf16 [(b*3328 + n')][c]  (k-contiguous rows for the MFMA GEMM)
//   XWW bf16 [b][c][n']          (padded windowed planes, pads ZEROED)
// ---------------------------------------------------------------------------
__launch_bounds__(256)
__global__ void xnt_make2(const float* __restrict__ x, const float* __restrict__ ab,
                          unsigned short* __restrict__ XNt, unsigned short* __restrict__ XWW)
{
    const int c0 = blockIdx.x * 64;      // channel chunk
    const int j1 = blockIdx.y;           // window row id
    const int b  = blockIdx.z;
    __shared__ unsigned short lt[64 * LTS];   // [c][px], px = h1*56 + w
    __shared__ float aa[64], bb[64];
    const int tid = threadIdx.x;
    if (tid < 64) { aa[tid] = ab[c0 + tid]; bb[tid] = ab[256 + c0 + tid]; }
    __syncthreads();

    // Phase A: load 64c x 7rows x 56w fp32, affine, cvt bf16 -> LDS
    for (int idx = tid; idx < 6272; idx += 256) {       // 64 * 98 float4
        const int c = idx / 98, f = idx - 98 * c;
        const int h1 = f / 14, w4 = (f - 14 * h1) * 4;
        const float4 v = *reinterpret_cast<const float4*>(
            &x[((size_t)(b * NC) + c0 + c) * NHW + (h1 * 8 + j1) * 56 + w4]);
        const float a = aa[c], bv = bb[c];
        union { ushort4 u; __hip_bfloat16 h[4]; } pk;
        pk.h[0] = __float2bfloat16(fmaf(a, v.x, bv));
        pk.h[1] = __float2bfloat16(fmaf(a, v.y, bv));
        pk.h[2] = __float2bfloat16(fmaf(a, v.z, bv));
        pk.h[3] = __float2bfloat16(fmaf(a, v.w, bv));
        *reinterpret_cast<ushort4*>(&lt[c * LTS + h1 * 56 + w4]) = pk.u;
    }
    __syncthreads();

    // Phase B: XWW planes: per (c, j2) one padded window run of 52 (13 ushort4)
    for (int idx = tid; idx < 6656; idx += 256) {       // 64c * 8j2 * 13
        const int c = idx / 104, r = idx - 104 * c;
        const int j2 = r / 13, q4 = (r - 13 * j2) * 4;
        unsigned short tmp[4];
#pragma unroll
        for (int e = 0; e < 4; ++e) {
            const int p = q4 + e;
            if (p < 49) {
                const int h1p = p / 7, w1 = p - 7 * h1p;
                tmp[e] = lt[c * LTS + h1p * 56 + w1 * 8 + j2];
            } else {
                tmp[e] = 0;                              // zero pad (+0.0 bf16)
            }
        }
        ushort4 v; v.x = tmp[0]; v.y = tmp[1]; v.z = tmp[2]; v.w = tmp[3];
        *reinterpret_cast<ushort4*>(
            &XWW[((size_t)(b * NC) + c0 + c) * NPW + (j1 * 8 + j2) * 52 + q4]) = v;
    }

    // Phase C: XNt rows: per (p, j2, c4): 4 channels of one windowed row
    for (int idx = tid; idx < 6272; idx += 256) {       // 49p * 8j2 * 16c4
        const int p = idx >> 7;                          // 0..48
        const int r = idx & 127;
        const int j2 = r >> 4, c4 = (r & 15) * 4;
        const int h1p = p / 7, w1 = p - 7 * h1p;
        const int px = h1p * 56 + w1 * 8 + j2;
        ushort4 v;
        v.x = lt[(c4 + 0) * LTS + px];
        v.y = lt[(c4 + 1) * LTS + px];
        v.z = lt[(c4 + 2) * LTS + px];
        v.w = lt[(c4 + 3) * LTS + px];
        *reinterpret_cast<ushort4*>(
            &XNt[((size_t)b * NPW + (j1 * 8 + j2) * 52 + p) * 256 + c0 + c4]) = v;
    }
}

// ---------------------------------------------------------------------------
// K2: QKV 1x1-conv as bf16 MFMA GEMM. Out[o][nn'] = sum_c Wb[o][c]*XNt[nn'][c].
//   o in [0,512)  (Q,K): QKt[b][n'][512] k-major.
//   o in [512,768) (V):  plane-major Vb[c][n'].
// ---------------------------------------------------------------------------
__launch_bounds__(256)
__global__ void gemm_qkv_mfma(const unsigned short* __restrict__ XNt,
                              const unsigned short* __restrict__ Wb,
                              const float* __restrict__ bias,
                              unsigned short* __restrict__ QKt,
                              unsigned short* __restrict__ Vb)
{
    __shared__ unsigned short As[128 * 72];   // W tile   [o][k]
    __shared__ unsigned short Bs[128 * 72];   // XNt tile [n][k]
    const int t = threadIdx.x;
    const int nn0 = blockIdx.x * 128;
    const int o0 = blockIdx.y * 128;
    const int lane = t & 63;
    const int wid = t >> 6;
    const int lr = lane & 15, lg = lane >> 4;
    const int wo = (wid >> 1) * 64;
    const int wn = (wid & 1) * 64;

    f32x4 acc[4][4];
#pragma unroll
    for (int i = 0; i < 4; ++i)
#pragma unroll
        for (int j = 0; j < 4; ++j)
            acc[i][j] = (f32x4){0.f, 0.f, 0.f, 0.f};

    for (int kt = 0; kt < 4; ++kt) {
        const int k0 = kt * 64;
#pragma unroll
        for (int it = 0; it < 4; ++it) {
            const int idx = it * 256 + t;     // 0..1023
            const int row = idx >> 3;         // 0..127
            const int k8 = (idx & 7) * 8;     // 0..56
            *reinterpret_cast<uint4*>(&As[row * 72 + k8]) =
                *reinterpret_cast<const uint4*>(&Wb[(size_t)(o0 + row) * 256 + k0 + k8]);
            *reinterpret_cast<uint4*>(&Bs[row * 72 + k8]) =
                *reinterpret_cast<const uint4*>(&XNt[(size_t)(nn0 + row) * 256 + k0 + k8]);
        }
        __syncthreads();
#pragma unroll
        for (int ks = 0; ks < 2; ++ks) {
            const int kk = ks * 32 + lg * 8;
            bf16x8 af[4], bfr[4];
#pragma unroll
            for (int i = 0; i < 4; ++i) {
                af[i]  = *reinterpret_cast<const bf16x8*>(&As[(wo + i * 16 + lr) * 72 + kk]);
                bfr[i] = *reinterpret_cast<const bf16x8*>(&Bs[(wn + i * 16 + lr) * 72 + kk]);
            }
#pragma unroll
            for (int i = 0; i < 4; ++i)
#pragma unroll
                for (int j = 0; j < 4; ++j)
                    acc[i][j] = __builtin_amdgcn_mfma_f32_16x16x32_bf16(
                        af[i], bfr[j], acc[i][j], 0, 0, 0);
        }
        __syncthreads();
    }

    // Epilogue: per osub pass, 32 o-rows x 128 n-cols through LDS (aliases As).
    float* Ts = reinterpret_cast<float*>(As);  // 32 x 132 fp32 = 16.5 KB
#pragma unroll
    for (int osub = 0; osub < 4; ++osub) {
        const float4 b4 = *reinterpret_cast<const float4*>(&bias[o0 + wo + osub * 16 + 4 * lg]);
        const int rowb = (wid >> 1) * 16 + 4 * lg;
#pragma unroll
        for (int j = 0; j < 4; ++j) {
            const int col = wn + j * 16 + lr;
            Ts[(rowb + 0) * 132 + col] = acc[osub][j][0] + b4.x;
            Ts[(rowb + 1) * 132 + col] = acc[osub][j][1] + b4.y;
            Ts[(rowb + 2) * 132 + col] = acc[osub][j][2] + b4.z;
            Ts[(rowb + 3) * 132 + col] = acc[osub][j][3] + b4.w;
        }
        __syncthreads();
        if (o0 < 512) {
            // Q/K: k-major QKt[b][n'][512], transposed read of Ts columns
#pragma unroll
            for (int p = 0; p < 4; ++p) {
                const int item = p * 256 + t;     // 0..1023
                const int n = item >> 3;          // 0..127
                const int half = (item >> 2) & 1;
                const int o4 = (item & 3) * 4;
                union { ushort4 u; __hip_bfloat16 h[4]; } pk;
#pragma unroll
                for (int e = 0; e < 4; ++e)
                    pk.h[e] = __float2bfloat16(Ts[(half * 16 + o4 + e) * 132 + n]);
                const int nn = nn0 + n;
                const int bb2 = nn / NPW;
                const int np = nn - bb2 * NPW;
                const int o = o0 + half * 64 + osub * 16 + o4;
                *reinterpret_cast<ushort4*>(&QKt[((size_t)bb2 * NPW + np) * 512 + o]) = pk.u;
            }
        } else {
            // V: plane-major [c][n'] (c = o-512)
#pragma unroll
            for (int p = 0; p < 4; ++p) {
                const int idx = p * 256 + t;      // 0..1023
                const int row = idx >> 5;         // 0..31
                const int c4 = (idx & 31) * 4;    // 0..124
                const float4 v = *reinterpret_cast<const float4*>(&Ts[row * 132 + c4]);
                const int o = o0 + (row >> 4) * 64 + osub * 16 + (row & 15);
                const int nn = nn0 + c4;
                const int bb2 = nn / NPW;
                const int n = nn - bb2 * NPW;     // padded-windowed n'
                union { ushort4 u; __hip_bfloat16 h[4]; } pk;
                pk.h[0] = __float2bfloat16(v.x);
                pk.h[1] = __float2bfloat16(v.y);
                pk.h[2] = __float2bfloat16(v.z);
                pk.h[3] = __float2bfloat16(v.w);
                *reinterpret_cast<ushort4*>(&Vb[((size_t)bb2 * 256 + (o - 512)) * NPW + n]) = pk.u;
            }
        }
        __syncthreads();
    }
}

// ---------------------------------------------------------------------------
// K4/K6: FFN 1x1-conv as bf16 MFMA GEMM (K=256, O=256). B operand staged with
// TRANSPOSE-IN-LDS directly from the plane-major source:
//   SRCF32=1 (ffn1): B from xa fp32 (windowed order); OUTPUT bf16 T.
//   SRCF32=0 (ffn2): B from U bf16 (normal order); OUTPUT fp32 + shortcut.
// ---------------------------------------------------------------------------
template<bool RES, bool SRCF32>
__launch_bounds__(256)
__global__ void gemm_ffn_mfma(const float* __restrict__ BF,
                              const unsigned short* __restrict__ BU,
                              const unsigned short* __restrict__ Wb2,
                              const float* __restrict__ bias,
                              const float* __restrict__ res, float* __restrict__ outF,
                              unsigned short* __restrict__ outU)
{
    __shared__ unsigned short As[128 * 72];   // W tile [o][k]
    __shared__ unsigned short Bs[128 * 72];   // act tile [n][k]
    const int t = threadIdx.x;
    const int o0 = blockIdx.x * 128;
    const int nn0 = blockIdx.y * 128;
    const int lane = t & 63;
    const int wid = t >> 6;
    const int lr = lane & 15, lg = lane >> 4;
    const int wo = (wid >> 1) * 64;
    const int wn = (wid & 1) * 64;

    f32x4 acc[4][4];
#pragma unroll
    for (int i = 0; i < 4; ++i)
#pragma unroll
        for (int j = 0; j < 4; ++j)
            acc[i][j] = (f32x4){0.f, 0.f, 0.f, 0.f};

    // B source row (32 n per thread, 32|3136 so no plane straddle)
    const int cl = t & 63;                 // channel within k-tile
    const int nseg = (t >> 6) * 32;        // n offset within tile
    const int nnB = nn0 + nseg;
    const int b2B = nnB / NHW;
    const int nB = nnB - b2B * NHW;

    for (int kt = 0; kt < 4; ++kt) {
        const int k0 = kt * 64;
        // A stage (weights, k-major): 4 iters x 16B
#pragma unroll
        for (int it = 0; it < 4; ++it) {
            const int idx = it * 256 + t;
            const int row = idx >> 3;
            const int k8 = (idx & 7) * 8;
            *reinterpret_cast<uint4*>(&As[row * 72 + k8]) =
                *reinterpret_cast<const uint4*>(&Wb2[(size_t)(o0 + row) * 256 + k0 + k8]);
        }
        // B stage: transpose from plane-major source
        {
            unsigned short* bd = &Bs[nseg * 72 + cl];
            if (SRCF32) {
                const float* src = BF + ((size_t)(b2B * NC) + k0 + cl) * NHW + nB;
#pragma unroll
                for (int q = 0; q < 8; ++q) {
                    const float4 vv = *reinterpret_cast<const float4*>(src + q * 4);
                    bd[(q * 4 + 0) * 72] = f2bu(vv.x);
                    bd[(q * 4 + 1) * 72] = f2bu(vv.y);
                    bd[(q * 4 + 2) * 72] = f2bu(vv.z);
                    bd[(q * 4 + 3) * 72] = f2bu(vv.w);
                }
            } else {
                const unsigned short* src = BU + ((size_t)(b2B * NC) + k0 + cl) * NHW + nB;
#pragma unroll
                for (int q = 0; q < 8; ++q) {
                    const ushort4 uu = *reinterpret_cast<const ushort4*>(src + q * 4);
                    bd[(q * 4 + 0) * 72] = uu.x;
                    bd[(q * 4 + 1) * 72] = uu.y;
                    bd[(q * 4 + 2) * 72] = uu.z;
                    bd[(q * 4 + 3) * 72] = uu.w;
                }
            }
        }
        __syncthreads();
#pragma unroll
        for (int ks = 0; ks < 2; ++ks) {
            const int kk = ks * 32 + lg * 8;
            bf16x8 af[4], bfr[4];
#pragma unroll
            for (int i = 0; i < 4; ++i) {
                af[i]  = *reinterpret_cast<const bf16x8*>(&As[(wo + i * 16 + lr) * 72 + kk]);
                bfr[i] = *reinterpret_cast<const bf16x8*>(&Bs[(wn + i * 16 + lr) * 72 + kk]);
            }
#pragma unroll
            for (int i = 0; i < 4; ++i)
#pragma unroll
                for (int j = 0; j < 4; ++j)
                    acc[i][j] = __builtin_amdgcn_mfma_f32_16x16x32_bf16(
                        af[i], bfr[j], acc[i][j], 0, 0, 0);
        }
        __syncthreads();
    }

    float* Ts = reinterpret_cast<float*>(As);  // 32 x 132 fp32
#pragma unroll
    for (int osub = 0; osub < 4; ++osub) {
        const float4 b4 = *reinterpret_cast<const float4*>(&bias[o0 + wo + osub * 16 + 4 * lg]);
        const int rowb = (wid >> 1) * 16 + 4 * lg;
#pragma unroll
        for (int j = 0; j < 4; ++j) {
            const int col = wn + j * 16 + lr;
            Ts[(rowb + 0) * 132 + col] = acc[osub][j][0] + b4.x;
            Ts[(rowb + 1) * 132 + col] = acc[osub][j][1] + b4.y;
            Ts[(rowb + 2) * 132 + col] = acc[osub][j][2] + b4.z;
            Ts[(rowb + 3) * 132 + col] = acc[osub][j][3] + b4.w;
        }
        __syncthreads();
#pragma unroll
        for (int p = 0; p < 4; ++p) {
            const int idx = p * 256 + t;      // 0..1023
            const int row = idx >> 5;         // 0..31
            const int c4 = (idx & 31) * 4;    // 0..124
            float4 v = *reinterpret_cast<const float4*>(&Ts[row * 132 + c4]);
            const int o = o0 + (row >> 4) * 64 + osub * 16 + (row & 15);
            const int nn = nn0 + c4;
            const int b2 = nn / NHW;
            const int n = nn - b2 * NHW;      // float4 never straddles (NHW%4==0)
            const size_t po = ((size_t)(b2 * NC + o)) * NHW + n;
            if (SRCF32) {                     // ffn1 -> bf16 T
                union { ushort4 u; __hip_bfloat16 h[4]; } pk;
                pk.h[0] = __float2bfloat16(v.x);
                pk.h[1] = __float2bfloat16(v.y);
                pk.h[2] = __float2bfloat16(v.z);
                pk.h[3] = __float2bfloat16(v.w);
                *reinterpret_cast<ushort4*>(&outU[po]) = pk.u;
            } else {                          // ffn2 -> fp32 + shortcut
                if (RES) {
                    const float4 rv = *reinterpret_cast<const float4*>(&res[po]);
                    v.x += rv.x; v.y += rv.y; v.z += rv.z; v.w += rv.w;
                }
                *reinterpret_cast<float4*>(&outF[po]) = v;
            }
        }
        __syncthreads();
    }
}

// ---------------------------------------------------------------------------
// K3: MFMA attention. ONE WAVE per (window, head), 64-thread blocks, zero
// barriers. Q/K fragments direct from global k-major QKt; swapped QK^T
// (S^T = mfma(K,Q)) for near-local softmax (2 shuffles/q-group).
// LDS SHRUNK 17920 -> 13568 B for occupancy (R8: LDS-capped at 9 blocks/CU,
// VALUBusy 50% w/ 2.25 waves/SIMD):
//   P[64][72] @0 (9216B; 144B rows -> 2-way bank alias = free)
//   VT[32][68] @9216 (4352B; 136B rows -> conflict-free b64 reads)
//   X buffer DELETED: dw-conv xn inputs re-read from global XWW (L1/L2-hot,
//   same lines staging just loaded -> no HBM FETCH delta).
//   post-PV overlay in dead P: wclB bf16 [1568] @0, SP[32][52] @3200.
// xa written WINDOWED (R6 lesson: stride-8 normal stores = 7.4x write amp).
// ---------------------------------------------------------------------------
__launch_bounds__(64)
__global__ void attn_mfma(const unsigned short* __restrict__ QKt,
                          const unsigned short* __restrict__ Vb,
                          const unsigned short* __restrict__ XWW,
                          const float* __restrict__ wcomb,
                          const float* __restrict__ bsumg,
                          float* __restrict__ xa)
{
    const int j = blockIdx.x;            // window id 0..63
    const int head = blockIdx.y;         // 0..7
    const int b = blockIdx.z;
    const int c0 = head * 32;
    const int lane = threadIdx.x;
    const int lr = lane & 15, lg = lane >> 4;

    __shared__ __align__(16) char smem[13568];
    unsigned short* P  = (unsigned short*)smem;             // [64][72], rows=q cols=k
    unsigned short* VT = (unsigned short*)(smem + 9216);    // [32][68]
    unsigned short* wclB = (unsigned short*)smem;           // [1568] bf16, post-PV alias
    unsigned short* SP = (unsigned short*)(smem + 3200);    // [32][52], post-PV alias

    // ---- early global loads: Q/K fragments (direct) + V/X rows into regs
    const size_t qkbase = ((size_t)b * NPW + j * 52) * 512 + c0 + lg * 8;
    uint4 aqr[4], bkr[4];
#pragma unroll
    for (int mi = 0; mi < 4; ++mi) {
        const unsigned short* rp = QKt + qkbase + (size_t)(mi * 16 + lr) * 512;
        aqr[mi] = *reinterpret_cast<const uint4*>(rp);
        bkr[mi] = *reinterpret_cast<const uint4*>(rp + 256);
    }
    const int dd = lane >> 1;                    // V row 0..31
    const int qn = (lane & 1) ? 6 : 7;           // chunks per lane
    const int qb = (lane & 1) * 7;               // chunk base
    const size_t pbase = ((size_t)(b * NC) + c0 + dd) * NPW + j * 52;
    ushort4 uvr[7], uxr[7];
#pragma unroll
    for (int ii = 0; ii < 7; ++ii)
        if (ii < qn) {
            const int q4 = (qb + ii) * 4;
            uvr[ii] = *reinterpret_cast<const ushort4*>(&Vb[pbase + q4]);
            uxr[ii] = *reinterpret_cast<const ushort4*>(&XWW[pbase + q4]);
        }

    // ---- S^T = K Q via MFMA (swapped operands, fp32 accum).
    // acc[mi][ni]: rows k = mi*16+lg*4+reg, cols q = ni*16+lr.
    f32x4 acc[4][4];
#pragma unroll
    for (int mi = 0; mi < 4; ++mi)
#pragma unroll
        for (int ni = 0; ni < 4; ++ni)
            acc[mi][ni] = (f32x4){0.f, 0.f, 0.f, 0.f};
    {
        union { uint4 u; bf16x8 v; } ca, cb;
#pragma unroll
        for (int mi = 0; mi < 4; ++mi)
#pragma unroll
            for (int ni = 0; ni < 4; ++ni) {
                cb.u = bkr[mi]; ca.u = aqr[ni];
                acc[mi][ni] = __builtin_amdgcn_mfma_f32_16x16x32_bf16(
                    cb.v, ca.v, acc[mi][ni], 0, 0, 0);
            }
    }

    // ---- V(+X) -> VT LDS (scheduled under softmax); pad masking
#pragma unroll
    for (int ii = 0; ii < 7; ++ii)
        if (ii < qn) {
            const int q4 = (qb + ii) * 4;
            union { ushort4 u; unsigned short s[4]; } uo;
            const unsigned short* vs = (const unsigned short*)&uvr[ii];
            const unsigned short* xs2 = (const unsigned short*)&uxr[ii];
#pragma unroll
            for (int e = 0; e < 4; ++e) {
                const float vv = bu2f(vs[e]) + bu2f(xs2[e]);
                uo.s[e] = (q4 + e >= 49) ? (unsigned short)0 : f2bu(vv);
            }
            *reinterpret_cast<ushort4*>(&VT[dd * 68 + q4]) = uo.u;
        }
    if (lane & 1) {                       // zero VT cols 52..63 (PV K-pad)
        ushort4 z; z.x = 0; z.y = 0; z.z = 0; z.w = 0;
        *reinterpret_cast<ushort4*>(&VT[dd * 68 + 52]) = z;
        *reinterpret_cast<ushort4*>(&VT[dd * 68 + 56]) = z;
        *reinterpret_cast<ushort4*>(&VT[dd * 68 + 60]) = z;
    }

    // ---- softmax: per lane, per ni (q = ni*16+lr): 16 local k values,
    // local tree max/sum + 2 shuffles each.
    const float sc = 0.17677669529663687f;
    const int kb = lg * 4;
#pragma unroll
    for (int ni = 0; ni < 4; ++ni) {
        float v[4][4];
#pragma unroll
        for (int mi = 0; mi < 4; ++mi)
#pragma unroll
            for (int reg = 0; reg < 4; ++reg) {
                const float raw = acc[mi][ni][reg] * sc;
                v[mi][reg] = (mi * 16 + kb + reg < 49) ? raw : -1e30f;
            }
        float m = -1e30f;
#pragma unroll
        for (int mi = 0; mi < 4; ++mi) {
            const float a0 = fmaxf(v[mi][0], v[mi][1]);
            const float a1 = fmaxf(v[mi][2], v[mi][3]);
            m = fmaxf(m, fmaxf(a0, a1));
        }
        m = fmaxf(m, __shfl_xor(m, 16));
        m = fmaxf(m, __shfl_xor(m, 32));
        float s = 0.f;
#pragma unroll
        for (int mi = 0; mi < 4; ++mi)
#pragma unroll
            for (int reg = 0; reg < 4; ++reg) {
                const float e = __expf(v[mi][reg] - m);   // invalid -> 0
                v[mi][reg] = e;
                s += e;
            }
        s += __shfl_xor(s, 16);
        s += __shfl_xor(s, 32);
        const float inv = 1.f / s;
        // store P[q][k] (P^T from registers), stride 72
        unsigned short* Pq = &P[(ni * 16 + lr) * 72];
#pragma unroll
        for (int mi = 0; mi < 4; ++mi)
#pragma unroll
            for (int reg = 0; reg < 4; ++reg)
                Pq[mi * 16 + kb + reg] = f2bu(v[mi][reg] * inv);
    }

    // ---- O = P @ V via MFMA (K-dim 64, 2 steps); VT rows via 2x b64
    f32x4 acc2[4][2];
#pragma unroll
    for (int mi = 0; mi < 4; ++mi)
#pragma unroll
        for (int ni = 0; ni < 2; ++ni)
            acc2[mi][ni] = (f32x4){0.f, 0.f, 0.f, 0.f};
#pragma unroll
    for (int ks = 0; ks < 2; ++ks) {
        bf16x8 ap[4];
#pragma unroll
        for (int mi = 0; mi < 4; ++mi)
            ap[mi] = *reinterpret_cast<const bf16x8*>(&P[(mi * 16 + lr) * 72 + ks * 32 + lg * 8]);
        bf16x8 bv2[2];
#pragma unroll
        for (int ni = 0; ni < 2; ++ni) {
            union { uint2 u[2]; bf16x8 v; } cv;
            cv.u[0] = *reinterpret_cast<const uint2*>(&VT[(ni * 16 + lr) * 68 + ks * 32 + lg * 8]);
            cv.u[1] = *reinterpret_cast<const uint2*>(&VT[(ni * 16 + lr) * 68 + ks * 32 + lg * 8 + 4]);
            bv2[ni] = cv.v;
        }
#pragma unroll
        for (int mi = 0; mi < 4; ++mi)
#pragma unroll
            for (int ni = 0; ni < 2; ++ni)
                acc2[mi][ni] = __builtin_amdgcn_mfma_f32_16x16x32_bf16(
                    ap[mi], bv2[ni], acc2[mi][ni], 0, 0, 0);
    }
    __builtin_amdgcn_sched_barrier(0);   // keep wclB/SP stores below all P reads

    // ---- spa[d][p] bf16 + wcomb bf16 into dead P region
#pragma unroll
    for (int mi = 0; mi < 4; ++mi)
#pragma unroll
        for (int ni = 0; ni < 2; ++ni)
#pragma unroll
            for (int reg = 0; reg < 4; ++reg) {
                const int p = mi * 16 + lg * 4 + reg;
                if (p < 49)
                    SP[(ni * 16 + lr) * 52 + p] = f2bu(acc2[mi][ni][reg]);
            }
    for (int i = lane; i < 392; i += 64) {
        const float4 wv4 = *reinterpret_cast<const float4*>(&wcomb[c0 * 49 + i * 4]);
        ushort4 wu;
        wu.x = f2bu(wv4.x); wu.y = f2bu(wv4.y); wu.z = f2bu(wv4.z); wu.w = f2bu(wv4.w);
        *reinterpret_cast<ushort4*>(&wclB[i * 4]) = wu;
    }

    // ---- combined 7x7 dw conv + 0.25*spa + bsum + v residual; WINDOWED store.
    // xn inputs read directly from global XWW (L1/L2-hot).
    const size_t xgbase = ((size_t)(b * NC) + c0) * NPW + j * 52;
    for (int it = 0; it < 4; ++it) {
        const int item = it * 64 + lane;
        if (item < 224) {
            const int d = item / 7, h1 = item - 7 * d;
            const float bsv = bsumg[c0 + d];
            const unsigned short* xrow = XWW + xgbase + (size_t)d * NPW;
            float accw[7];
#pragma unroll
            for (int w1 = 0; w1 < 7; ++w1) {
                const int p = h1 * 7 + w1;
                accw[w1] = fmaf(0.25f, bu2f(SP[d * 52 + p]), bsv + bu2f(VT[d * 68 + p]));
            }
#pragma unroll
            for (int dy = 0; dy < 7; ++dy) {
                const int ry = h1 + dy - 3;
                const bool rok = (ry >= 0) && (ry < 7);
                const int ryc = rok ? ry : 0;
                const unsigned short* xr7 = xrow + ryc * 7;
                float xr[7];
#pragma unroll
                for (int i2 = 0; i2 < 7; ++i2) {
                    const float xv = bu2f(xr7[i2]);
                    xr[i2] = rok ? xv : 0.f;
                }
#pragma unroll
                for (int dx = 0; dx < 7; ++dx) {
                    const float wv = bu2f(wclB[d * 49 + dy * 7 + dx]);
#pragma unroll
                    for (int w1 = 0; w1 < 7; ++w1) {
                        const int rx = w1 + dx - 3;
                        if (rx >= 0 && rx < 7) accw[w1] = fmaf(wv, xr[rx], accw[w1]);
                    }
                }
            }
            float* xap = xa + ((size_t)(b * NC + c0 + d)) * NHW + j * 49 + h1 * 7;
#pragma unroll
            for (int w1 = 0; w1 < 7; ++w1) xap[w1] = accw[w1];
        }
    }
}

// ---------------------------------------------------------------------------
// K5: per-(b,c)-plane: 3x3 depthwise conv (conv_local) + SiLU on T
// (T bf16 WINDOWED -> LDS-normal -> stencil -> U bf16 NORMAL), plus in-place
// windowed->normal permute of xa (shortcut for the final GEMM).
// ---------------------------------------------------------------------------
__launch_bounds__(256)
__global__ void dw3_silu(const unsigned short* __restrict__ T, const float* __restrict__ wloc,
                         const float* __restrict__ bloc, unsigned short* __restrict__ Uu,
                         float* xa)
{
    const int c = blockIdx.x, b = blockIdx.y;
    const size_t pb = ((size_t)b * NC + c) * NHW;
    __shared__ float pl[56 * 57];        // T, normal order, stride-57 rows
    __shared__ float xpl[3136];          // xa, normal order
    const int tid = threadIdx.x;
    const ushort4* t4 = reinterpret_cast<const ushort4*>(T + pb);
    const float4* x4 = reinterpret_cast<const float4*>(xa + pb);
    for (int i = tid; i < 784; i += 256) {
        const ushort4 tv = t4[i];
        const float4 xv = x4[i];
        const float tt[4] = {bu2f(tv.x), bu2f(tv.y), bu2f(tv.z), bu2f(tv.w)};
        const float xx[4] = {xv.x, xv.y, xv.z, xv.w};
#pragma unroll
        for (int e = 0; e < 4; ++e) {
            const int n = 4 * i + e;
            const int j = n / 49, p = n - 49 * j;
            const int h1 = p / 7, w1 = p - 7 * h1;
            const int h = h1 * 8 + (j >> 3), w = w1 * 8 + (j & 7);
            pl[h * 57 + w] = tt[e];
            xpl[h * 56 + w] = xx[e];
        }
    }
    __syncthreads();

    float wk[9];
#pragma unroll
    for (int k = 0; k < 9; ++k) wk[k] = wloc[c * 9 + k];
    const float bs = bloc[c];
    unsigned short* up = Uu + pb;
    for (int i4 = tid; i4 < 784; i4 += 256) {
        ushort4 pk;
        unsigned short* pks = (unsigned short*)&pk;
#pragma unroll
        for (int e = 0; e < 4; ++e) {
            const int i = 4 * i4 + e;
            const int h = i / 56, w = i - 56 * h;
            float acc = bs;
#pragma unroll
            for (int dy = -1; dy <= 1; ++dy) {
                const int hh = h + dy;
                if (hh < 0 || hh >= 56) continue;
#pragma unroll
                for (int dx = -1; dx <= 1; ++dx) {
                    const int ww = w + dx;
                    if (ww < 0 || ww >= 56) continue;
                    acc = fmaf(wk[(dy + 1) * 3 + (dx + 1)], pl[hh * 57 + ww], acc);
                }
            }
            pks[e] = f2bu(acc / (1.f + __expf(-acc)));   // silu
        }
        *reinterpret_cast<ushort4*>(&up[4 * i4]) = pk;
    }

    float4* xo4 = reinterpret_cast<float4*>(xa + pb);
    for (int i = tid; i < 784; i += 256)
        xo4[i] = make_float4(xpl[4 * i], xpl[4 * i + 1], xpl[4 * i + 2], xpl[4 * i + 3]);
}

// ---------------------------------------------------------------------------
// Launch. Workspace layout (floats):
//   [0,512)              : BN affine a[256], b[256]
//   wcomb = W+512        : 256*49
//   bsum  = W+13056      : 256
//   part  = W+13312      : 256*8*2 partial BN sums -> ends 17408
//   Wb    = W+17408      : 768*256 bf16 (98304 fl) -> ends 115712
//   Wfb   = W+115712     : 256*256 bf16 (32768 fl) -> ends 148480
//   Wob   = W+148480     : 256*256 bf16 (32768 fl) -> ends 181248
//   xa    = W+181248     : NA fl — XNt alias (dead after QKV GEMM), attn
//                          output WINDOWED fp32, NORMAL after K5 (in-place)
//   R     = xa+NA        : 54,525,952 fl shared region:
//     phase 1: QKt us [b][3328][512] | Vb planes | XWW planes
//     phase 2: T bf16 (windowed order) + Uu bf16 (normal) in QKt region.
//   total ~ 321.6 MB
// ---------------------------------------------------------------------------
extern "C" void kernel_launch(void* const* d_in, const int* in_sizes, int n_in,
                              void* d_out, int out_size, void* d_ws, size_t ws_size,
                              hipStream_t stream)
{
    (void)in_sizes; (void)n_in; (void)out_size; (void)ws_size;
    const float* x    = (const float*)d_in[0];
    const float* g    = (const float*)d_in[1];
    const float* be   = (const float*)d_in[2];
    const float* qkvw = (const float*)d_in[3];
    const float* qkvb = (const float*)d_in[4];
    const float* w3   = (const float*)d_in[5];
    const float* b3   = (const float*)d_in[6];
    const float* w5   = (const float*)d_in[7];
    const float* b5   = (const float*)d_in[8];
    const float* w7   = (const float*)d_in[9];
    const float* b7   = (const float*)d_in[10];
    const float* fiw  = (const float*)d_in[11];
    const float* fib  = (const float*)d_in[12];
    const float* clw  = (const float*)d_in[13];
    const float* clb  = (const float*)d_in[14];
    const float* fow  = (const float*)d_in[15];
    const float* fob  = (const float*)d_in[16];
    float* out = (float*)d_out;

    float* W     = (float*)d_ws;
    float* ab    = W;
    float* wcomb = W + 512;
    float* bsum  = W + 13056;
    float* part  = W + 13312;
    __hip_bfloat16* Wb  = (__hip_bfloat16*)(W + 17408);
    __hip_bfloat16* Wfb = (__hip_bfloat16*)(W + 115712);
    __hip_bfloat16* Wob = (__hip_bfloat16*)(W + 148480);
    float* xa    = W + 181248;
    unsigned short* XNt = (unsigned short*)xa;              // dead after QKV GEMM
    float* R     = xa + NA;
    unsigned short* QKt = (unsigned short*)R;               // [b][3328][512]
    unsigned short* Vb  = QKt + (size_t)NB * NPW * 512;
    unsigned short* XWW = Vb + (size_t)NB * 256 * NPW;
    unsigned short* T   = (unsigned short*)R;               // bf16, in QKt region
    unsigned short* Uu  = T + NA;                           // bf16, in QKt region

    bn_part<<<dim3(256, 8), dim3(256), 0, stream>>>(x, part);
    bn_fin<<<dim3(256), dim3(256), 0, stream>>>(part, g, be, w3, b3, w5, b5, w7, b7,
                                                qkvw, fiw, fow, ab, wcomb, bsum,
                                                Wb, Wfb, Wob);
    xnt_make2<<<dim3(4, 8, NB), dim3(256), 0, stream>>>(x, ab, XNt, XWW);
    gemm_qkv_mfma<<<dim3(832, 6), dim3(256), 0, stream>>>(
        XNt, (const unsigned short*)Wb, qkvb, QKt, Vb);
    attn_mfma<<<dim3(64, 8, NB), dim3(64), 0, stream>>>(
        QKt, Vb, XWW, wcomb, bsum, xa);
    gemm_ffn_mfma<false, true><<<dim3(2, 784), dim3(256), 0, stream>>>(
        xa, nullptr, (const unsigned short*)Wfb, fib, nullptr, nullptr, T);
    dw3_silu<<<dim3(256, NB), dim3(256), 0, stream>>>(T, clw, clb, Uu, xa);
    gemm_ffn_mfma<true, false><<<dim3(2, 784), dim3(256), 0, stream>>>(
        nullptr, Uu, (const unsigned short*)Wob, fob, xa, out, nullptr);
}